// Round 3
// baseline (261.824 us; speedup 1.0000x reference)
//
#include <hip/hip_runtime.h>
#include <math.h>

// v3: occupancy-focused restructure of the full-width strip design.
// - TH=8 rows/block -> 2048 blocks (8/CU, one clean round)
// - LDS exactly 20480 B (10 rows x 512 floats) -> 8 blocks/CU by LDS
// - no guard columns: image-edge columns handled by predicated LDS reads
//   (divergent only in threads 0 and 255)
// - __launch_bounds__(256,8) caps VGPR at 64 -> 32 waves/CU eligible
// - kernel1 stores UNNORMALIZED SUM OF SQUARES; max(sumsq) is monotone with
//   max(sqrt(sumsq)), so sqrt moves to the normalize pass: out = sqrt(acc*inv)
#define HH 512
#define WW 512
#define TH 8           // output rows per block
#define NROWS 10       // blur rows held (TH + 2 sobel halo)
#define NLOAD 14       // img rows loaded (TH + 6)
#define VBW 512        // LDS row stride in floats (exactly the image width)

__global__ __launch_bounds__(256, 8)
void edge_fused_v3(const float* __restrict__ img,
                   const float* __restrict__ gauss,
                   float* __restrict__ out,
                   unsigned int* __restrict__ gmax) {
    __shared__ float vb[NROWS][VBW];   // 20480 B exactly -> 8 blocks/CU

    const int tid = threadIdx.x;
    const int bid = blockIdx.x;
    const int strip = bid & 63;        // 512/8 = 64 strips
    const int b     = bid >> 6;        // batch index
    const int ry0 = strip * TH;
    const int c0  = tid * 2;           // this thread owns columns c0, c0+1

    const float g0 = gauss[0], g1 = gauss[1], g2 = gauss[2], g3 = gauss[3], g4 = gauss[4];

    const bool interior = (ry0 >= 3) && (ry0 + TH + 3 <= HH);  // strips 1..62
    const bool haveA = (c0 >= 2);        // false only for thread 0
    const bool haveC = (c0 < WW - 2);    // false only for thread 255
    const float2 Z = make_float2(0.f, 0.f);

    float acc0[TH], acc1[TH];
#pragma unroll
    for (int o = 0; o < TH; ++o) { acc0[o] = 0.f; acc1[o] = 0.f; }

    for (int c = 0; c < 3; ++c) {
        const float* imgc = img + ((size_t)(b * 3 + c) * HH) * WW;

        // ---- phase 1: vertical gaussian -> LDS (cols c0,c0+1 as float2) ----
        float2 w[NLOAD];
        if (interior) {
#pragma unroll
            for (int i = 0; i < NLOAD; ++i)
                w[i] = *(const float2*)(imgc + (size_t)(ry0 - 3 + i) * WW + c0);
        } else {
#pragma unroll
            for (int i = 0; i < NLOAD; ++i) {
                const int y = ry0 - 3 + i;
                w[i] = (y >= 0 && y < HH)
                     ? *(const float2*)(imgc + (size_t)y * WW + c0)
                     : Z;
            }
        }
#pragma unroll
        for (int r = 0; r < NROWS; ++r) {
            float2 s;
            s.x = g0*w[r].x + g1*w[r+1].x + g2*w[r+2].x + g3*w[r+3].x + g4*w[r+4].x;
            s.y = g0*w[r].y + g1*w[r+1].y + g2*w[r+2].y + g3*w[r+3].y + g4*w[r+4].y;
            *(float2*)&vb[r][c0] = s;
        }
        __syncthreads();

        // ---- phase 2a: horizontal gaussian into registers (img zero-pad) ----
        float2 bl[NROWS];
#pragma unroll
        for (int r = 0; r < NROWS; ++r) {
            const float2 A  = haveA ? *(const float2*)&vb[r][c0 - 2] : Z;
            const float2 Bv = *(const float2*)&vb[r][c0];
            const float2 C  = haveC ? *(const float2*)&vb[r][c0 + 2] : Z;
            bl[r].x = g0*A.x  + g1*A.y  + g2*Bv.x + g3*Bv.y + g4*C.x;
            bl[r].y = g0*A.y  + g1*Bv.x + g2*Bv.y + g3*C.x  + g4*C.y;
        }
        __syncthreads();

        // ---- phase 2b: blur back in place; zero rows outside image
        //      (reference zero-pads the BLUR before the sobel conv) ----
        if (interior) {
#pragma unroll
            for (int r = 0; r < NROWS; ++r)
                *(float2*)&vb[r][c0] = bl[r];
        } else {
#pragma unroll
            for (int r = 0; r < NROWS; ++r) {
                const int yb = ry0 - 1 + r;
                float2 v = bl[r];
                if (yb < 0 || yb >= HH) { v.x = 0.f; v.y = 0.f; }
                *(float2*)&vb[r][c0] = v;
            }
        }
        __syncthreads();

        // ---- phase 3: sobel (cross-correlation) via u/v row combos ----
        // u = p[x-1]-p[x+1], v = p[x-1]+2p[x]+p[x+1]
        // gx(y) = u(y-1)+2u(y)+u(y+1) ; gy(y) = v(y-1)-v(y+1)
        float u0[2], v0[2], u1[2], v1[2];
#pragma unroll
        for (int r = 0; r < 2; ++r) {
            const float2 A  = haveA ? *(const float2*)&vb[r][c0 - 2] : Z;
            const float2 Bv = *(const float2*)&vb[r][c0];
            const float2 C  = haveC ? *(const float2*)&vb[r][c0 + 2] : Z;
            u0[r] = A.y - Bv.y;   v0[r] = A.y  + 2.f*Bv.x + Bv.y;
            u1[r] = Bv.x - C.x;   v1[r] = Bv.x + 2.f*Bv.y + C.x;
        }
#pragma unroll
        for (int o = 0; o < TH; ++o) {
            const int r = o + 2;
            const float2 A  = haveA ? *(const float2*)&vb[r][c0 - 2] : Z;
            const float2 Bv = *(const float2*)&vb[r][c0];
            const float2 C  = haveC ? *(const float2*)&vb[r][c0 + 2] : Z;
            const float nu0 = A.y - Bv.y,  nv0 = A.y  + 2.f*Bv.x + Bv.y;
            const float nu1 = Bv.x - C.x,  nv1 = Bv.x + 2.f*Bv.y + C.x;
            const float gx0 = u0[0] + 2.f*u0[1] + nu0;
            const float gy0 = v0[0] - nv0;
            const float gx1 = u1[0] + 2.f*u1[1] + nu1;
            const float gy1 = v1[0] - nv1;
            acc0[o] += gx0*gx0 + gy0*gy0;
            acc1[o] += gx1*gx1 + gy1*gy1;
            u0[0] = u0[1]; u0[1] = nu0;  v0[0] = v0[1]; v0[1] = nv0;
            u1[0] = u1[1]; u1[1] = nu1;  v1[0] = v1[1]; v1[1] = nv1;
        }
        __syncthreads();   // protect vb before next channel overwrites
    }

    // ---- epilogue: store SUMSQ (sqrt deferred), block max of sumsq ----
    float m = 0.f;
#pragma unroll
    for (int o = 0; o < TH; ++o) {
        float2 v; v.x = acc0[o]; v.y = acc1[o];
        *(float2*)(out + ((size_t)b * HH + (ry0 + o)) * WW + c0) = v;
        m = fmaxf(m, fmaxf(v.x, v.y));
    }
#pragma unroll
    for (int off = 32; off > 0; off >>= 1)
        m = fmaxf(m, __shfl_xor(m, off, 64));
    if ((tid & 63) == 0) vb[0][tid >> 6] = m;   // vb reused as scratch
    __syncthreads();
    if (tid == 0) {
        const float bm = fmaxf(fmaxf(vb[0][0], vb[0][1]), fmaxf(vb[0][2], vb[0][3]));
        // values non-negative: float bits are monotone as unsigned
        atomicMax(gmax, __float_as_uint(bm));
    }
}

__global__ __launch_bounds__(256)
void normalize_v3(float* __restrict__ out,
                  const unsigned int* __restrict__ gmax,
                  int n4) {
    // out holds sumsq; max holds max(sumsq).  sqrt(acc)/sqrt(max) = sqrt(acc/max)
    const float inv = 1.0f / __uint_as_float(*gmax);
    float4* o4 = (float4*)out;
    const int stride = gridDim.x * blockDim.x;
    for (int i = blockIdx.x * blockDim.x + threadIdx.x; i < n4; i += stride) {
        float4 v = o4[i];
        v.x = sqrtf(v.x * inv);
        v.y = sqrtf(v.y * inv);
        v.z = sqrtf(v.z * inv);
        v.w = sqrtf(v.w * inv);
        o4[i] = v;
    }
}

extern "C" void kernel_launch(void* const* d_in, const int* in_sizes, int n_in,
                              void* d_out, int out_size, void* d_ws, size_t ws_size,
                              hipStream_t stream) {
    const float* img   = (const float*)d_in[0];
    const float* gauss = (const float*)d_in[1];
    float* out = (float*)d_out;

    unsigned int* gmax = (unsigned int*)d_ws;
    hipMemsetAsync(gmax, 0, sizeof(unsigned int), stream);   // ws re-poisoned each launch

    const int B = 32;
    const int blocks = B * (HH / TH);   // 32 * 64 = 2048  (8 blocks/CU, 1 round)
    edge_fused_v3<<<blocks, 256, 0, stream>>>(img, gauss, out, gmax);

    const int n4 = out_size / 4;        // 2,097,152 float4s
    normalize_v3<<<4096, 256, 0, stream>>>(out, gmax, n4);
}

// Round 4
// 214.783 us; speedup vs baseline: 1.2190x; 1.2190x over previous
//
#include <hip/hip_runtime.h>
#include <math.h>

// v4: v3 geometry (TH=8, 2048 blocks, 20.6KB LDS) with the spill fixed and
// the horizontal blur FUSED into the sobel phase.
// - __launch_bounds__(256,4): 128-VGPR cap, ~85 needed -> NO scratch spill
//   (v3's (256,8)=64-cap spilled: WRITE_SIZE 293MB, VALUBusy 10%)
// - single LDS buffer holds the VERTICAL gaussian result; each thread
//   recomputes its 4 horizontal-blur columns on the fly in the sobel loop:
//   kills the bl[10] register array and 2 of 4 barriers per channel
// - guard columns (img cols -2,-1,512,513 = 0) at idx {0,1,514,515}
// - XCD-chunked swizzle: neighbor strips co-resident per XCD L2 (halo reuse)
// - kernel1 stores sum-of-squares; sqrt folded into normalize (monotone max)
#define HH 512
#define WW 512
#define TH 8           // output rows per block
#define NROWS 10       // blur rows held (TH + 2 sobel halo)
#define NLOAD 14       // img rows loaded (TH + 6)
#define VBW 516        // LDS row stride: img col x lives at idx x+2

__global__ __launch_bounds__(256, 4)
void edge_fused_v4(const float* __restrict__ img,
                   const float* __restrict__ gauss,
                   float* __restrict__ out,
                   unsigned int* __restrict__ gmax) {
    __shared__ float vb[NROWS][VBW];   // 10*516*4 = 20640 B

    const int tid = threadIdx.x;
    // XCD-chunked bijective swizzle (2048 blocks, 8 XCDs, 256/chunk)
    const int bid = (blockIdx.x & 7) * 256 + (blockIdx.x >> 3);
    const int strip = bid & 63;        // 512/8 = 64 strips per image
    const int b     = bid >> 6;        // batch index
    const int ry0 = strip * TH;
    const int c0  = tid * 2;           // this thread owns columns c0, c0+1

    const float g0 = gauss[0], g1 = gauss[1], g2 = gauss[2], g3 = gauss[3], g4 = gauss[4];

    const bool interior = (ry0 >= 3) && (ry0 + TH + 3 <= HH);  // strips 1..62
    const bool haveA = (tid != 0);     // col c0-3 exists
    const bool haveC = (tid != 255);   // col c0+4 exists
    const float2 Z = make_float2(0.f, 0.f);

    // one-time guard zeros: idx 0,1 (cols -2,-1) and 514,515 (cols 512,513).
    // phase1 writes idx 2..513 only, fused phase never writes -> stay valid.
    if (tid < 40) {
        const int r = tid >> 2, k = tid & 3;
        vb[r][(k < 2) ? k : 512 + k] = 0.f;
    }

    float acc0[TH], acc1[TH];
#pragma unroll
    for (int o = 0; o < TH; ++o) { acc0[o] = 0.f; acc1[o] = 0.f; }

    for (int c = 0; c < 3; ++c) {
        const float* imgc = img + ((size_t)(b * 3 + c) * HH) * WW;

        // ---- phase 1: vertical gaussian -> LDS (cols c0,c0+1 as float2) ----
        float2 w[NLOAD];
        if (interior) {
#pragma unroll
            for (int i = 0; i < NLOAD; ++i)
                w[i] = *(const float2*)(imgc + (size_t)(ry0 - 3 + i) * WW + c0);
        } else {
#pragma unroll
            for (int i = 0; i < NLOAD; ++i) {
                const int y = ry0 - 3 + i;
                w[i] = (y >= 0 && y < HH)
                     ? *(const float2*)(imgc + (size_t)y * WW + c0)
                     : Z;
            }
        }
#pragma unroll
        for (int r = 0; r < NROWS; ++r) {
            float2 s;
            s.x = g0*w[r].x + g1*w[r+1].x + g2*w[r+2].x + g3*w[r+3].x + g4*w[r+4].x;
            s.y = g0*w[r].y + g1*w[r+1].y + g2*w[r+2].y + g3*w[r+3].y + g4*w[r+4].y;
            *(float2*)&vb[r][c0 + 2] = s;   // idx c0+2 (even, 8B aligned)
        }
        __syncthreads();

        // ---- phase 2 (fused): horizontal gaussian on the fly + sobel ----
        // blur[x] needed at x = c0-1, c0, c0+1, c0+2 (img-col space).
        // vb idx of img col x is x+2. sobel zero-pad: blur cols -1 and 512,
        // and blur rows outside [0,512), are exactly 0.
        float u0p[2], v0p[2], u1p[2], v1p[2];
#pragma unroll
        for (int r = 0; r < NROWS; ++r) {
            const int yb = ry0 - 1 + r;
            const float rm = (yb >= 0 && yb < HH) ? 1.f : 0.f;
            const float mA = haveA ? rm : 0.f;   // also forces blur[-1] = 0
            const float mC = haveC ? rm : 0.f;   // also forces blur[512] = 0

            const float  Lf = haveA ? vb[r][c0 - 1] : 0.f;  // col c0-3
            const float2 A  = *(const float2*)&vb[r][c0];     // cols c0-2,c0-1
            const float2 Bv = *(const float2*)&vb[r][c0 + 2]; // cols c0,  c0+1
            const float2 C  = *(const float2*)&vb[r][c0 + 4]; // cols c0+2,c0+3
            const float  Rf = haveC ? vb[r][c0 + 6] : 0.f;  // col c0+4

            const float blm1 = (g0*Lf   + g1*A.x  + g2*A.y  + g3*Bv.x + g4*Bv.y) * mA;
            const float bl0  = (g0*A.x  + g1*A.y  + g2*Bv.x + g3*Bv.y + g4*C.x ) * rm;
            const float bl1  = (g0*A.y  + g1*Bv.x + g2*Bv.y + g3*C.x  + g4*C.y ) * rm;
            const float bl2  = (g0*Bv.x + g1*Bv.y + g2*C.x  + g3*C.y  + g4*Rf  ) * mC;

            // u = p[x-1]-p[x+1], v = p[x-1]+2p[x]+p[x+1]
            const float nu0 = blm1 - bl1;
            const float nv0 = blm1 + 2.f*bl0 + bl1;
            const float nu1 = bl0 - bl2;
            const float nv1 = bl0 + 2.f*bl1 + bl2;

            if (r < 2) {
                u0p[r] = nu0; v0p[r] = nv0;
                u1p[r] = nu1; v1p[r] = nv1;
            } else {
                const int o = r - 2;
                const float gx0 = u0p[0] + 2.f*u0p[1] + nu0;
                const float gy0 = v0p[0] - nv0;
                const float gx1 = u1p[0] + 2.f*u1p[1] + nu1;
                const float gy1 = v1p[0] - nv1;
                acc0[o] += gx0*gx0 + gy0*gy0;
                acc1[o] += gx1*gx1 + gy1*gy1;
                u0p[0] = u0p[1]; u0p[1] = nu0;  v0p[0] = v0p[1]; v0p[1] = nv0;
                u1p[0] = u1p[1]; u1p[1] = nu1;  v1p[0] = v1p[1]; v1p[1] = nv1;
            }
        }
        __syncthreads();   // protect vb before next channel's phase 1
    }

    // ---- epilogue: store SUMSQ (sqrt deferred), block max -> atomicMax ----
    float m = 0.f;
#pragma unroll
    for (int o = 0; o < TH; ++o) {
        float2 v; v.x = acc0[o]; v.y = acc1[o];
        *(float2*)(out + ((size_t)b * HH + (ry0 + o)) * WW + c0) = v;
        m = fmaxf(m, fmaxf(v.x, v.y));
    }
#pragma unroll
    for (int off = 32; off > 0; off >>= 1)
        m = fmaxf(m, __shfl_xor(m, off, 64));
    if ((tid & 63) == 0) vb[0][tid >> 6] = m;   // vb reused as scratch
    __syncthreads();
    if (tid == 0) {
        const float bm = fmaxf(fmaxf(vb[0][0], vb[0][1]), fmaxf(vb[0][2], vb[0][3]));
        // values non-negative: float bits monotone as unsigned
        atomicMax(gmax, __float_as_uint(bm));
    }
}

__global__ __launch_bounds__(256)
void normalize_v4(float* __restrict__ out,
                  const unsigned int* __restrict__ gmax,
                  int n4) {
    // out holds sumsq; gmax holds max(sumsq). sqrt(a)/sqrt(mx) = sqrt(a/mx)
    const float inv = 1.0f / __uint_as_float(*gmax);
    float4* o4 = (float4*)out;
    const int stride = gridDim.x * blockDim.x;
    for (int i = blockIdx.x * blockDim.x + threadIdx.x; i < n4; i += stride) {
        float4 v = o4[i];
        v.x = sqrtf(v.x * inv);
        v.y = sqrtf(v.y * inv);
        v.z = sqrtf(v.z * inv);
        v.w = sqrtf(v.w * inv);
        o4[i] = v;
    }
}

extern "C" void kernel_launch(void* const* d_in, const int* in_sizes, int n_in,
                              void* d_out, int out_size, void* d_ws, size_t ws_size,
                              hipStream_t stream) {
    const float* img   = (const float*)d_in[0];
    const float* gauss = (const float*)d_in[1];
    float* out = (float*)d_out;

    unsigned int* gmax = (unsigned int*)d_ws;
    hipMemsetAsync(gmax, 0, sizeof(unsigned int), stream);   // ws re-poisoned each launch

    const int B = 32;
    const int blocks = B * (HH / TH);   // 32 * 64 = 2048
    edge_fused_v4<<<blocks, 256, 0, stream>>>(img, gauss, out, gmax);

    const int n4 = out_size / 4;        // 2,097,152 float4s
    normalize_v4<<<4096, 256, 0, stream>>>(out, gmax, n4);
}

// Round 5
// 214.279 us; speedup vs baseline: 1.2219x; 1.0024x over previous
//
#include <hip/hip_runtime.h>
#include <math.h>

// v5 = v4 math (passing) + two codegen controls that kill the scratch spill:
//  1. '#pragma unroll 1' on the channel loop: v4's WRITE_SIZE=131MB came from
//     the compiler unrolling c=0..2 and hoisting the NEXT channel's 14 global
//     loads (28 VGPR) over the barrier into the current sobel phase -> ~147
//     live > 128 cap -> spill. The loop back-edge forbids that hoist.
//  2. sched_barrier(0) per fused-loop row: bounds ds_read hoisting (10 rows x
//     8 floats = 80 VGPR if freely hoisted) to ~1 row. 28 waves/CU of TLP
//     covers the LDS latency instead.
// Geometry unchanged: TH=8, 2048 blocks, LDS 20640B -> 7 blocks/CU,
// XCD-chunked swizzle, guard columns, sumsq stored (sqrt folded into
// normalize; max is monotone under sqrt).
#define HH 512
#define WW 512
#define TH 8           // output rows per block
#define NROWS 10       // blur rows held (TH + 2 sobel halo)
#define NLOAD 14       // img rows loaded (TH + 6)
#define VBW 516        // LDS row stride: img col x lives at idx x+2

__global__ __launch_bounds__(256, 4)
void edge_fused_v5(const float* __restrict__ img,
                   const float* __restrict__ gauss,
                   float* __restrict__ out,
                   unsigned int* __restrict__ gmax) {
    __shared__ float vb[NROWS][VBW];   // 10*516*4 = 20640 B

    const int tid = threadIdx.x;
    // XCD-chunked bijective swizzle (2048 blocks = 8 XCDs x 256)
    const int bid = (blockIdx.x & 7) * 256 + (blockIdx.x >> 3);
    const int strip = bid & 63;        // 512/8 = 64 strips per image
    const int b     = bid >> 6;        // batch index
    const int ry0 = strip * TH;
    const int c0  = tid * 2;           // this thread owns columns c0, c0+1

    const float g0 = gauss[0], g1 = gauss[1], g2 = gauss[2], g3 = gauss[3], g4 = gauss[4];

    const bool interior = (ry0 >= 3) && (ry0 + TH + 3 <= HH);  // strips 1..62
    const bool haveA = (tid != 0);
    const bool haveC = (tid != 255);
    const float2 Z = make_float2(0.f, 0.f);

    // one-time guard zeros: idx 0,1 (img cols -2,-1) and 514,515 (cols 512,513).
    // phase1 writes idx 2..513 only -> these stay valid for all channels.
    // covered by the first __syncthreads() inside the channel loop.
    if (tid < 40) {
        const int r = tid >> 2, k = tid & 3;
        vb[r][(k < 2) ? k : 512 + k] = 0.f;
    }

    float acc0[TH], acc1[TH];
#pragma unroll
    for (int o = 0; o < TH; ++o) { acc0[o] = 0.f; acc1[o] = 0.f; }

#pragma unroll 1   // DO NOT unroll: cross-channel load hoisting caused the spill
    for (int c = 0; c < 3; ++c) {
        const float* imgc = img + ((size_t)(b * 3 + c) * HH) * WW;

        // ---- phase 1: vertical gaussian -> LDS (cols c0,c0+1 as float2) ----
        float2 w[NLOAD];
        if (interior) {
#pragma unroll
            for (int i = 0; i < NLOAD; ++i)
                w[i] = *(const float2*)(imgc + (size_t)(ry0 - 3 + i) * WW + c0);
        } else {
#pragma unroll
            for (int i = 0; i < NLOAD; ++i) {
                const int y = ry0 - 3 + i;
                w[i] = (y >= 0 && y < HH)
                     ? *(const float2*)(imgc + (size_t)y * WW + c0)
                     : Z;
            }
        }
#pragma unroll
        for (int r = 0; r < NROWS; ++r) {
            float2 s;
            s.x = g0*w[r].x + g1*w[r+1].x + g2*w[r+2].x + g3*w[r+3].x + g4*w[r+4].x;
            s.y = g0*w[r].y + g1*w[r+1].y + g2*w[r+2].y + g3*w[r+3].y + g4*w[r+4].y;
            *(float2*)&vb[r][c0 + 2] = s;   // idx c0+2 (even, 8B aligned)
        }
        __syncthreads();

        // ---- phase 2 (fused): horizontal gaussian on the fly + sobel ----
        // blur[x] needed at x = c0-1..c0+2 (img-col space); vb idx = x+2.
        // sobel zero-pad: blur col -1/512 and rows outside [0,512) are 0.
        float u0p[2], v0p[2], u1p[2], v1p[2];
#pragma unroll
        for (int r = 0; r < NROWS; ++r) {
            const int yb = ry0 - 1 + r;
            const float rm = (yb >= 0 && yb < HH) ? 1.f : 0.f;
            const float mA = haveA ? rm : 0.f;   // also forces blur[-1] = 0
            const float mC = haveC ? rm : 0.f;   // also forces blur[512] = 0

            const float  Lf = haveA ? vb[r][c0 - 1] : 0.f;    // col c0-3
            const float2 A  = *(const float2*)&vb[r][c0];     // cols c0-2,c0-1
            const float2 Bv = *(const float2*)&vb[r][c0 + 2]; // cols c0,  c0+1
            const float2 C  = *(const float2*)&vb[r][c0 + 4]; // cols c0+2,c0+3
            const float  Rf = haveC ? vb[r][c0 + 6] : 0.f;    // col c0+4

            const float blm1 = (g0*Lf   + g1*A.x  + g2*A.y  + g3*Bv.x + g4*Bv.y) * mA;
            const float bl0  = (g0*A.x  + g1*A.y  + g2*Bv.x + g3*Bv.y + g4*C.x ) * rm;
            const float bl1  = (g0*A.y  + g1*Bv.x + g2*Bv.y + g3*C.x  + g4*C.y ) * rm;
            const float bl2  = (g0*Bv.x + g1*Bv.y + g2*C.x  + g3*C.y  + g4*Rf  ) * mC;

            // u = p[x-1]-p[x+1], v = p[x-1]+2p[x]+p[x+1]
            const float nu0 = blm1 - bl1;
            const float nv0 = blm1 + 2.f*bl0 + bl1;
            const float nu1 = bl0 - bl2;
            const float nv1 = bl0 + 2.f*bl1 + bl2;

            if (r < 2) {
                u0p[r] = nu0; v0p[r] = nv0;
                u1p[r] = nu1; v1p[r] = nv1;
            } else {
                const int o = r - 2;
                const float gx0 = u0p[0] + 2.f*u0p[1] + nu0;
                const float gy0 = v0p[0] - nv0;
                const float gx1 = u1p[0] + 2.f*u1p[1] + nu1;
                const float gy1 = v1p[0] - nv1;
                acc0[o] += gx0*gx0 + gy0*gy0;
                acc1[o] += gx1*gx1 + gy1*gy1;
                u0p[0] = u0p[1]; u0p[1] = nu0;  v0p[0] = v0p[1]; v0p[1] = nv0;
                u1p[0] = u1p[1]; u1p[1] = nu1;  v1p[0] = v1p[1]; v1p[1] = nv1;
            }
            // bound ds_read hoisting to ~one row of live values (spill control)
            __builtin_amdgcn_sched_barrier(0);
        }
        __syncthreads();   // protect vb before next channel's phase 1
    }

    // ---- epilogue: store SUMSQ (sqrt deferred), block max -> atomicMax ----
    float m = 0.f;
#pragma unroll
    for (int o = 0; o < TH; ++o) {
        float2 v; v.x = acc0[o]; v.y = acc1[o];
        *(float2*)(out + ((size_t)b * HH + (ry0 + o)) * WW + c0) = v;
        m = fmaxf(m, fmaxf(v.x, v.y));
    }
#pragma unroll
    for (int off = 32; off > 0; off >>= 1)
        m = fmaxf(m, __shfl_xor(m, off, 64));
    if ((tid & 63) == 0) vb[0][tid >> 6] = m;   // vb reused as scratch
    __syncthreads();
    if (tid == 0) {
        const float bm = fmaxf(fmaxf(vb[0][0], vb[0][1]), fmaxf(vb[0][2], vb[0][3]));
        // values non-negative: float bits monotone as unsigned
        atomicMax(gmax, __float_as_uint(bm));
    }
}

__global__ __launch_bounds__(256)
void normalize_v5(float* __restrict__ out,
                  const unsigned int* __restrict__ gmax,
                  int n4) {
    // out holds sumsq; gmax holds max(sumsq). sqrt(a)/sqrt(mx) = sqrt(a*inv)
    const float inv = 1.0f / __uint_as_float(*gmax);
    float4* o4 = (float4*)out;
    const int stride = gridDim.x * blockDim.x;
    for (int i = blockIdx.x * blockDim.x + threadIdx.x; i < n4; i += stride) {
        float4 v = o4[i];
        v.x = sqrtf(v.x * inv);
        v.y = sqrtf(v.y * inv);
        v.z = sqrtf(v.z * inv);
        v.w = sqrtf(v.w * inv);
        o4[i] = v;
    }
}

extern "C" void kernel_launch(void* const* d_in, const int* in_sizes, int n_in,
                              void* d_out, int out_size, void* d_ws, size_t ws_size,
                              hipStream_t stream) {
    const float* img   = (const float*)d_in[0];
    const float* gauss = (const float*)d_in[1];
    float* out = (float*)d_out;

    unsigned int* gmax = (unsigned int*)d_ws;
    hipMemsetAsync(gmax, 0, sizeof(unsigned int), stream);   // ws re-poisoned each launch

    const int B = 32;
    const int blocks = B * (HH / TH);   // 32 * 64 = 2048
    edge_fused_v5<<<blocks, 256, 0, stream>>>(img, gauss, out, gmax);

    const int n4 = out_size / 4;        // 2,097,152 float4s
    normalize_v5<<<4096, 256, 0, stream>>>(out, gmax, n4);
}

// Round 6
// 194.690 us; speedup vs baseline: 1.3448x; 1.1006x over previous
//
#include <hip/hip_runtime.h>
#include <math.h>

// v6 = v4/v5 math (identical, passing) with register pressure bounded BY
// CONSTRUCTION instead of by pragmas (v5 proved pragmas were no-ops here):
//  1. channel loop trip count 'nc' is a RUNTIME kernel argument -> no pass can
//     unroll it -> no cross-channel live ranges. (v4/v5 allocated the full
//     128-reg cap (VGPR_Count is 2-reg granules) and still spilled ~186B/thr
//     -> live pressure ~140: only explicable by cross-channel/phase merging.)
//  2. phase 2 is two statically-unrolled 5-row halves with a compiler memory
//     barrier between them: caps LDS-read hoisting at 5 rows (~40 regs).
//     Carried between halves: u/v (8 regs) + acc (16 regs). All array indices
//     remain compile-time constants (no scratch from dynamic indexing).
// Geometry unchanged: TH=8, 2048 blocks, LDS 20640B, XCD-chunked swizzle,
// guard columns, sumsq stored (sqrt folded into normalize; max monotone).
#define HH 512
#define WW 512
#define TH 8           // output rows per block
#define NROWS 10       // blur rows held (TH + 2 sobel halo)
#define NLOAD 14       // img rows loaded (TH + 6)
#define VBW 516        // LDS row stride: img col x lives at idx x+2

// per-row sobel helper: computes nu0,nv0,nu1,nv1 for blur row r of this block.
// u = p[x-1]-p[x+1], v = p[x-1]+2p[x]+p[x+1]  (horizontal gaussian fused in)
#define ROWCALC(r)                                                            \
    const int yb = ry0 - 1 + (r);                                             \
    const float rm = (yb >= 0 && yb < HH) ? 1.f : 0.f;                        \
    const float mA = haveA ? rm : 0.f;                                        \
    const float mC = haveC ? rm : 0.f;                                        \
    const float  Lf = haveA ? vb[r][c0 - 1] : 0.f;                            \
    const float2 A  = *(const float2*)&vb[r][c0];                             \
    const float2 Bv = *(const float2*)&vb[r][c0 + 2];                         \
    const float2 C  = *(const float2*)&vb[r][c0 + 4];                         \
    const float  Rf = haveC ? vb[r][c0 + 6] : 0.f;                            \
    const float blm1 = (g0*Lf   + g1*A.x  + g2*A.y  + g3*Bv.x + g4*Bv.y) * mA;\
    const float bl0  = (g0*A.x  + g1*A.y  + g2*Bv.x + g3*Bv.y + g4*C.x ) * rm;\
    const float bl1  = (g0*A.y  + g1*Bv.x + g2*Bv.y + g3*C.x  + g4*C.y ) * rm;\
    const float bl2  = (g0*Bv.x + g1*Bv.y + g2*C.x  + g3*C.y  + g4*Rf  ) * mC;\
    const float nu0 = blm1 - bl1;                                             \
    const float nv0 = blm1 + 2.f*bl0 + bl1;                                   \
    const float nu1 = bl0 - bl2;                                              \
    const float nv1 = bl0 + 2.f*bl1 + bl2;

#define ROWACC(r, o) {                                                        \
    ROWCALC(r)                                                                \
    const float gx0 = u0p0 + 2.f*u0p1 + nu0;                                  \
    const float gy0 = v0p0 - nv0;                                             \
    const float gx1 = u1p0 + 2.f*u1p1 + nu1;                                  \
    const float gy1 = v1p0 - nv1;                                             \
    acc0[o] += gx0*gx0 + gy0*gy0;                                             \
    acc1[o] += gx1*gx1 + gy1*gy1;                                             \
    u0p0 = u0p1; u0p1 = nu0;  v0p0 = v0p1; v0p1 = nv0;                        \
    u1p0 = u1p1; u1p1 = nu1;  v1p0 = v1p1; v1p1 = nv1; }

__global__ __launch_bounds__(256, 4)
void edge_fused_v6(const float* __restrict__ img,
                   const float* __restrict__ gauss,
                   float* __restrict__ out,
                   unsigned int* __restrict__ gmax,
                   int nc) {
    __shared__ float vb[NROWS][VBW];   // 10*516*4 = 20640 B

    const int tid = threadIdx.x;
    // XCD-chunked bijective swizzle (2048 blocks = 8 XCDs x 256)
    const int bid = (blockIdx.x & 7) * 256 + (blockIdx.x >> 3);
    const int strip = bid & 63;        // 512/8 = 64 strips per image
    const int b     = bid >> 6;        // batch index
    const int ry0 = strip * TH;
    const int c0  = tid * 2;           // this thread owns columns c0, c0+1

    const float g0 = gauss[0], g1 = gauss[1], g2 = gauss[2], g3 = gauss[3], g4 = gauss[4];

    const bool interior = (ry0 >= 3) && (ry0 + TH + 3 <= HH);  // strips 1..62
    const bool haveA = (tid != 0);
    const bool haveC = (tid != 255);
    const float2 Z = make_float2(0.f, 0.f);

    // one-time guard zeros: idx 0,1 (img cols -2,-1) and 514,515 (512,513).
    // phase1 writes idx 2..513 only -> valid for all channels.
    if (tid < 40) {
        const int r = tid >> 2, k = tid & 3;
        vb[r][(k < 2) ? k : 512 + k] = 0.f;
    }

    float acc0[TH], acc1[TH];
#pragma unroll
    for (int o = 0; o < TH; ++o) { acc0[o] = 0.f; acc1[o] = 0.f; }

    for (int c = 0; c < nc; ++c) {   // nc is RUNTIME -> cannot unroll
        const float* imgc = img + ((size_t)(b * 3 + c) * HH) * WW;

        // ---- phase 1: vertical gaussian -> LDS (cols c0,c0+1 as float2) ----
        float2 w[NLOAD];
        if (interior) {
#pragma unroll
            for (int i = 0; i < NLOAD; ++i)
                w[i] = *(const float2*)(imgc + (size_t)(ry0 - 3 + i) * WW + c0);
        } else {
#pragma unroll
            for (int i = 0; i < NLOAD; ++i) {
                const int y = ry0 - 3 + i;
                w[i] = (y >= 0 && y < HH)
                     ? *(const float2*)(imgc + (size_t)y * WW + c0)
                     : Z;
            }
        }
#pragma unroll
        for (int r = 0; r < NROWS; ++r) {
            float2 s;
            s.x = g0*w[r].x + g1*w[r+1].x + g2*w[r+2].x + g3*w[r+3].x + g4*w[r+4].x;
            s.y = g0*w[r].y + g1*w[r+1].y + g2*w[r+2].y + g3*w[r+3].y + g4*w[r+4].y;
            *(float2*)&vb[r][c0 + 2] = s;   // idx c0+2 (even, 8B aligned)
        }
        __syncthreads();

        // ---- phase 2: fused horizontal gaussian + sobel, two 5-row halves ----
        float u0p0, u0p1, v0p0, v0p1, u1p0, u1p1, v1p0, v1p1;
        { ROWCALC(0) u0p0 = nu0; v0p0 = nv0; u1p0 = nu1; v1p0 = nv1; }
        { ROWCALC(1) u0p1 = nu0; v0p1 = nv0; u1p1 = nu1; v1p1 = nv1; }
        ROWACC(2, 0)
        ROWACC(3, 1)
        ROWACC(4, 2)
        asm volatile("" ::: "memory");   // half boundary: cap LDS-read hoisting
        ROWACC(5, 3)
        ROWACC(6, 4)
        ROWACC(7, 5)
        ROWACC(8, 6)
        ROWACC(9, 7)
        __syncthreads();   // protect vb before next channel's phase 1
    }

    // ---- epilogue: store SUMSQ (sqrt deferred), block max -> atomicMax ----
    float m = 0.f;
#pragma unroll
    for (int o = 0; o < TH; ++o) {
        float2 v; v.x = acc0[o]; v.y = acc1[o];
        *(float2*)(out + ((size_t)b * HH + (ry0 + o)) * WW + c0) = v;
        m = fmaxf(m, fmaxf(v.x, v.y));
    }
#pragma unroll
    for (int off = 32; off > 0; off >>= 1)
        m = fmaxf(m, __shfl_xor(m, off, 64));
    if ((tid & 63) == 0) vb[0][tid >> 6] = m;   // vb reused as scratch
    __syncthreads();
    if (tid == 0) {
        const float bm = fmaxf(fmaxf(vb[0][0], vb[0][1]), fmaxf(vb[0][2], vb[0][3]));
        // values non-negative: float bits monotone as unsigned
        atomicMax(gmax, __float_as_uint(bm));
    }
}

__global__ __launch_bounds__(256)
void normalize_v6(float* __restrict__ out,
                  const unsigned int* __restrict__ gmax,
                  int n4) {
    // out holds sumsq; gmax holds max(sumsq). sqrt(a)/sqrt(mx) = sqrt(a*inv)
    const float inv = 1.0f / __uint_as_float(*gmax);
    float4* o4 = (float4*)out;
    const int stride = gridDim.x * blockDim.x;
    for (int i = blockIdx.x * blockDim.x + threadIdx.x; i < n4; i += stride) {
        float4 v = o4[i];
        v.x = sqrtf(v.x * inv);
        v.y = sqrtf(v.y * inv);
        v.z = sqrtf(v.z * inv);
        v.w = sqrtf(v.w * inv);
        o4[i] = v;
    }
}

extern "C" void kernel_launch(void* const* d_in, const int* in_sizes, int n_in,
                              void* d_out, int out_size, void* d_ws, size_t ws_size,
                              hipStream_t stream) {
    const float* img   = (const float*)d_in[0];
    const float* gauss = (const float*)d_in[1];
    float* out = (float*)d_out;

    unsigned int* gmax = (unsigned int*)d_ws;
    hipMemsetAsync(gmax, 0, sizeof(unsigned int), stream);   // ws re-poisoned each launch

    const int B = 32;
    const int blocks = B * (HH / TH);   // 32 * 64 = 2048
    edge_fused_v6<<<blocks, 256, 0, stream>>>(img, gauss, out, gmax, 3);

    const int n4 = out_size / 4;        // 2,097,152 float4s
    normalize_v6<<<4096, 256, 0, stream>>>(out, gmax, n4);
}